// Round 6
// baseline (244.686 us; speedup 1.0000x reference)
//
#include <hip/hip_runtime.h>

// Causal depthwise conv1d: out[b,t,f] = sum_k w[k,f] * x[b, t-(K-1)+k, f] + b[f]
// B=4, T=8192, F=1024, K=4. float32.
//
// R1-R3 lesson: chunked per-block streams (2048 x 64KB, 4KB-strided waves)
// pin at ~2.5 TB/s regardless of per-wave MLP (1 vs 10) or occupancy (23-47%).
// => address-pattern-bound, not latency-bound.
// R4: clone the proven 6.3 TB/s copy structure — one flat sequential frontier.
// thread handles float4 i; neighbors x[i-256/512/768] trail by 4/8/12KB and
// hit L2/L3 (fetched moments earlier by neighboring blocks). XCD-chunked
// swizzle keeps trailing reads on the same XCD's L2.
// (R4/R5 benches were acquisition timeouts — rerunning identical kernel.)

constexpr int Tc   = 8192;
constexpr int F4   = 256;                  // float4s per feature row (F=1024)
constexpr int N4   = 4 * Tc * F4;          // total output float4s = 8M
constexpr int NBLK = 4096;
constexpr int NTHR = 256;
constexpr int ITERS = N4 / (NBLK * NTHR);  // 8
constexpr int GSTRIDE = NBLK * NTHR;       // 1M float4s per sweep

__global__ __launch_bounds__(256) void causal_conv1d_kernel(
    const float* __restrict__ x,
    const float* __restrict__ w,      // (K,1,F) -> w[k*F + f]
    const float* __restrict__ bias,   // (F,)
    float* __restrict__ out)
{
    // XCD-chunked swizzle: hw block bid runs on XCD bid%8; give it work chunk
    // (bid%8)*512 + bid/8 so each XCD owns a contiguous 512-block span.
    const int bid  = blockIdx.x;
    const int wblk = (bid & 7) * (NBLK / 8) + (bid >> 3);

    const int f  = threadIdx.x * 4;   // feature group (invariant across iters)
    const float4 w0 = *reinterpret_cast<const float4*>(w + 0 * 1024 + f);
    const float4 w1 = *reinterpret_cast<const float4*>(w + 1 * 1024 + f);
    const float4 w2 = *reinterpret_cast<const float4*>(w + 2 * 1024 + f);
    const float4 w3 = *reinterpret_cast<const float4*>(w + 3 * 1024 + f);
    const float4 bv = *reinterpret_cast<const float4*>(bias + f);

    const float4* __restrict__ x4 = reinterpret_cast<const float4*>(x);
    float4* __restrict__ o4       = reinterpret_cast<float4*>(out);

    const int i0 = wblk * NTHR + threadIdx.x;

#pragma unroll
    for (int it = 0; it < ITERS; ++it) {
        const int i = i0 + it * GSTRIDE;      // flat float4 index
        const int t = (i >> 8) & (Tc - 1);    // time step within batch

        float4 xc, xm1, xm2, xm3;
        if (t >= 3) {                          // wave-uniform fast path
            xc  = x4[i];
            xm1 = x4[i - 1 * F4];
            xm2 = x4[i - 2 * F4];
            xm3 = x4[i - 3 * F4];
        } else {                               // rows 0..2 of each batch
            const float4 z = make_float4(0.f, 0.f, 0.f, 0.f);
            xc  = x4[i];
            xm1 = (t >= 1) ? x4[i - 1 * F4] : z;
            xm2 = (t >= 2) ? x4[i - 2 * F4] : z;
            xm3 = z;
        }

        float4 o;
        o.x = fmaf(w3.x, xc.x, fmaf(w2.x, xm1.x, fmaf(w1.x, xm2.x, fmaf(w0.x, xm3.x, bv.x))));
        o.y = fmaf(w3.y, xc.y, fmaf(w2.y, xm1.y, fmaf(w1.y, xm2.y, fmaf(w0.y, xm3.y, bv.y))));
        o.z = fmaf(w3.z, xc.z, fmaf(w2.z, xm1.z, fmaf(w1.z, xm2.z, fmaf(w0.z, xm3.z, bv.z))));
        o.w = fmaf(w3.w, xc.w, fmaf(w2.w, xm1.w, fmaf(w1.w, xm2.w, fmaf(w0.w, xm3.w, bv.w))));

        o4[i] = o;
    }
}

extern "C" void kernel_launch(void* const* d_in, const int* in_sizes, int n_in,
                              void* d_out, int out_size, void* d_ws, size_t ws_size,
                              hipStream_t stream) {
    const float* x    = (const float*)d_in[0];
    const float* w    = (const float*)d_in[1];
    const float* bias = (const float*)d_in[2];
    float* out        = (float*)d_out;

    causal_conv1d_kernel<<<NBLK, NTHR, 0, stream>>>(x, w, bias, out);
}

// Round 8
// 227.498 us; speedup vs baseline: 1.0756x; 1.0756x over previous
//
#include <hip/hip_runtime.h>

// Causal depthwise conv1d: out[b,t,f] = sum_k w[k,f] * x[b, t-(K-1)+k, f] + b[f]
// B=4, T=8192, F=1024, K=4. float32.
//
// R1-R6: five structural variants (MLP 1..10, occupancy 23..73%, chunked and
// flat copy-clone frontiers, XCD swizzle) ALL pin at 2.3-2.6 TB/s, while
// fillBuffer in the same trace writes at 6.5 TB/s. Remaining suspect: the
// harness dirties d_in/d_out in L2/L3 right before each replay (restore copy +
// 0xAA poison); our cached loads/stores then fight dirty-line allocation.
// R7: R3 sliding-window structure (1x read traffic, materialized load batch)
// with NONTEMPORAL loads+stores (MUBUF nt) — pure HBM stream, no cache alloc.
// (R7 bench was an acquisition timeout — rerunning identical kernel.)

typedef float v4f __attribute__((ext_vector_type(4)));

constexpr int Tc = 8192;
constexpr int Fc = 1024;
constexpr int TCHUNK = 16;                 // t-rows per block
constexpr int CHUNKS = Tc / TCHUNK;        // 512
constexpr int NBLK = 4 * CHUNKS;           // 2048 blocks (B=4)

__global__ __launch_bounds__(256) void causal_conv1d_kernel(
    const float* __restrict__ x,
    const float* __restrict__ w,      // (K,1,F) -> w[k*F + f]
    const float* __restrict__ bias,   // (F,)
    float* __restrict__ out)
{
    const int f   = threadIdx.x * 4;  // feature group of 4
    const int bt  = blockIdx.x;
    const int b   = bt / CHUNKS;
    const int t0  = (bt % CHUNKS) * TCHUNK;

    const v4f w0 = *reinterpret_cast<const v4f*>(w + 0 * Fc + f);
    const v4f w1 = *reinterpret_cast<const v4f*>(w + 1 * Fc + f);
    const v4f w2 = *reinterpret_cast<const v4f*>(w + 2 * Fc + f);
    const v4f w3 = *reinterpret_cast<const v4f*>(w + 3 * Fc + f);
    const v4f bv = *reinterpret_cast<const v4f*>(bias + f);

    const float* xp = x   + (size_t)b * Tc * Fc + f;
    float*       op = out + (size_t)b * Tc * Fc + f;

    // Window rows t0-3..t0-1 (halo; read once, nt too — re-read cost is tiny)
    v4f xm3, xm2, xm1;
    if (t0 >= 3) {
        xm3 = __builtin_nontemporal_load(reinterpret_cast<const v4f*>(xp + (size_t)(t0 - 3) * Fc));
        xm2 = __builtin_nontemporal_load(reinterpret_cast<const v4f*>(xp + (size_t)(t0 - 2) * Fc));
        xm1 = __builtin_nontemporal_load(reinterpret_cast<const v4f*>(xp + (size_t)(t0 - 1) * Fc));
    } else {
        xm3 = (v4f)(0.f);
        xm2 = (v4f)(0.f);
        xm1 = (v4f)(0.f);
    }

    // ---------- phase 1: issue all TCHUNK independent nt loads ----------
    v4f xc[TCHUNK];
#pragma unroll
    for (int i = 0; i < TCHUNK; ++i) {
        xc[i] = __builtin_nontemporal_load(
            reinterpret_cast<const v4f*>(xp + (size_t)(t0 + i) * Fc));
    }

    // Fence: loads may not be sunk past this point.
    __builtin_amdgcn_sched_barrier(0);

    // ---------- phase 2: compute + nt store ----------
#pragma unroll
    for (int i = 0; i < TCHUNK; ++i) {
        v4f o = w3 * xc[i] + w2 * xm1 + w1 * xm2 + w0 * xm3 + bv;
        __builtin_nontemporal_store(o,
            reinterpret_cast<v4f*>(op + (size_t)(t0 + i) * Fc));
        xm3 = xm2; xm2 = xm1; xm1 = xc[i];
    }
}

extern "C" void kernel_launch(void* const* d_in, const int* in_sizes, int n_in,
                              void* d_out, int out_size, void* d_ws, size_t ws_size,
                              hipStream_t stream) {
    const float* x    = (const float*)d_in[0];
    const float* w    = (const float*)d_in[1];
    const float* bias = (const float*)d_in[2];
    float* out        = (float*)d_out;

    causal_conv1d_kernel<<<NBLK, 256, 0, stream>>>(x, w, bias, out);
}